// Round 3
// baseline (5999.180 us; speedup 1.0000x reference)
//
#include <hip/hip_runtime.h>
#include <hip/hip_bf16.h>
#include <math.h>

#define BB 256      // batch
#define TT 96       // seq len
#define PP 96       // pred len
#define CC 321      // enc_in
#define CP 352      // padded enc_in (11*32)
#define DD 512      // d_model
#define GG 2048     // 4*DD
#define NSTEPS 191  // 96 encoder + 95 decoder (decoder step 96 output is unused)

typedef __attribute__((ext_vector_type(8))) short bf16x8;
typedef __attribute__((ext_vector_type(4))) float f32x4;
typedef __hip_bfloat16 bf16;

// ---------------------------------------------------------------------------
// Instance norm over time: mean/stdev per (b,c); write normalized x to
// xnorm[t][b][c] (bf16, row pitch CP, pad cols pre-zeroed by memset).
__global__ void norm_kernel(const float* __restrict__ x, float* __restrict__ meanp,
                            float* __restrict__ stdp, bf16* __restrict__ xn) {
    int g = blockIdx.x * 256 + threadIdx.x;      // 0 .. BB*CC-1
    if (g >= BB * CC) return;
    int b = g / CC, c = g % CC;
    const float* xp = x + b * TT * CC + c;
    float s = 0.f;
    for (int t = 0; t < TT; ++t) s += xp[t * CC];
    float mu = s * (1.f / TT);
    float v = 0.f;
    for (int t = 0; t < TT; ++t) { float d0 = xp[t * CC] - mu; v += d0 * d0; }
    float sd = sqrtf(v * (1.f / TT) + 1e-5f);
    float rs = 1.f / sd;
    meanp[g] = mu;
    stdp[g] = sd;
    for (int t = 0; t < TT; ++t)
        xn[(t * BB + b) * CP + c] = __float2bfloat16((xp[t * CC] - mu) * rs);
}

// Cast fp32 [rows][cols] -> bf16 [rows][ldd] (pad cols pre-zeroed if ldd>cols)
__global__ void cast_pad_kernel(const float* __restrict__ src, bf16* __restrict__ dst,
                                int rows, int cols, int ldd) {
    int i = blockIdx.x * 256 + threadIdx.x;
    if (i >= rows * cols) return;
    int r = i / cols, c = i % cols;
    dst[r * ldd + c] = __float2bfloat16(src[i]);
}

// WpT[d][c] = Wp[c][d]  (bf16, row pitch CP, pad pre-zeroed)
__global__ void transpose_wp_kernel(const float* __restrict__ wp, bf16* __restrict__ wpt) {
    int i = blockIdx.x * 256 + threadIdx.x;      // over DD*CC
    if (i >= DD * CC) return;
    int d = i / CC, c = i % CC;
    wpt[d * CP + c] = __float2bfloat16(wp[c * DD + d]);
}

// bsum[j] = bih+bhh ; beff[j] = bih+bhh + dot(Wih[j,:], bp)   (fp32)
__global__ void bias_kernel(const float* __restrict__ Wih, const float* __restrict__ bih,
                            const float* __restrict__ bhh, const float* __restrict__ bp,
                            float* __restrict__ bsum, float* __restrict__ beff) {
    int j = blockIdx.x * 256 + threadIdx.x;      // 2048
    if (j >= GG) return;
    float s = bih[j] + bhh[j];
    float acc = 0.f;
    const float* w = Wih + j * CC;
    for (int c = 0; c < CC; ++c) acc += w[c] * bp[c];
    bsum[j] = s;
    beff[j] = s + acc;
}

// ---------------------------------------------------------------------------
// Generic 64x64 block MFMA core: C[m][n] = sum_k A[m][k] * Bt[n][k]
// 256 threads / 4 waves; wave w owns m-tile w (16 rows) x 4 n-tiles.
__device__ __forceinline__ void gemm_core_64x64(const bf16* A, int lda, const bf16* Bt,
                                                int ldb, int K, int m0, int n0,
                                                f32x4 acc[4]) {
    __shared__ unsigned short As[64][40];
    __shared__ unsigned short Bs[64][40];
    int tid = threadIdx.x;
    int w = tid >> 6, lane = tid & 63;
    int quad = lane >> 4, col = lane & 15;
    int lr = tid >> 2, lc = (tid & 3) * 8;
    for (int k0 = 0; k0 < K; k0 += 32) {
        __syncthreads();
        *(uint4*)&As[lr][lc] = *(const uint4*)&A[(size_t)(m0 + lr) * lda + k0 + lc];
        *(uint4*)&Bs[lr][lc] = *(const uint4*)&Bt[(size_t)(n0 + lr) * ldb + k0 + lc];
        __syncthreads();
        bf16x8 a = *(const bf16x8*)&As[w * 16 + col][quad * 8];
#pragma unroll
        for (int nt = 0; nt < 4; ++nt) {
            bf16x8 bfr = *(const bf16x8*)&Bs[nt * 16 + col][quad * 8];
            acc[nt] = __builtin_amdgcn_mfma_f32_16x16x32_bf16(a, bfr, acc[nt], 0, 0, 0);
        }
    }
}

// Weff[j][d] = Whh[j][d] + sum_c Wih[j][c]*Wp[c][d]   (bf16 out)
__global__ void weff_kernel(const bf16* __restrict__ WihP, const bf16* __restrict__ WpTP,
                            const float* __restrict__ Whh, bf16* __restrict__ WeffP) {
    f32x4 acc[4] = {{0,0,0,0},{0,0,0,0},{0,0,0,0},{0,0,0,0}};
    int m0 = blockIdx.y * 64, n0 = blockIdx.x * 64;
    gemm_core_64x64(WihP, CP, WpTP, CP, CP, m0, n0, acc);
    int tid = threadIdx.x, w = tid >> 6, lane = tid & 63;
    int quad = lane >> 4, col = lane & 15;
#pragma unroll
    for (int nt = 0; nt < 4; ++nt)
#pragma unroll
        for (int r = 0; r < 4; ++r) {
            int j = m0 + w * 16 + quad * 4 + r;
            int d = n0 + nt * 16 + col;
            WeffP[j * DD + d] = __float2bfloat16(acc[nt][r] + Whh[j * DD + d]);
        }
}

// Final projection + denorm: out[b][t][c] = (Hdec[t*BB+b,:]@Wp[c,:] + bp[c])*std + mean
__global__ void proj_kernel(const bf16* __restrict__ Hdec, const bf16* __restrict__ WpP,
                            const float* __restrict__ bp, const float* __restrict__ stdp,
                            const float* __restrict__ meanp, float* __restrict__ out) {
    f32x4 acc[4] = {{0,0,0,0},{0,0,0,0},{0,0,0,0},{0,0,0,0}};
    int m0 = blockIdx.x * 64, n0 = blockIdx.y * 64;
    gemm_core_64x64(Hdec, DD, WpP, DD, DD, m0, n0, acc);
    int tid = threadIdx.x, w = tid >> 6, lane = tid & 63;
    int quad = lane >> 4, col = lane & 15;
#pragma unroll
    for (int nt = 0; nt < 4; ++nt) {
        int c = n0 + nt * 16 + col;
        if (c >= CC) continue;
        float bpc = bp[c];
#pragma unroll
        for (int r = 0; r < 4; ++r) {
            int row = m0 + w * 16 + quad * 4 + r;   // = t*BB + b
            int t = row >> 8, b = row & 255;
            float y = acc[nt][r] + bpc;
            int sc = b * CC + c;
            out[(b * PP + t) * CC + c] = y * stdp[sc] + meanp[sc];
        }
    }
}

// ---------------------------------------------------------------------------
// Persistent recurrence kernel. 256 blocks x 128 threads, 1 block/CU
// (110 KB LDS), cooperative launch. Block (bt,dt) owns batches
// b0=bt*32..+31 and gate rows j = gate*512 + dt*16..+15 for all 4 gates.
// Weights LDS-resident; cell state register-resident for all 191 steps;
// only h (256 KB bf16) crosses global per step. Sync = per-b-tile 32-block
// barrier (8 independent groups), generation-counted, agent-scope.
// NOTE (R2 bug fix): a Whh row = 512 bf16 = 64 uint4, a Wih row = 352 bf16
// = 44 uint4. R2 staged 32/22 chunks per row -> upper half of LDS was
// uninitialized garbage -> NaN. Chunk counts corrected to 64/44.
__global__ __launch_bounds__(128, 1) void lstm_persistent(
        const bf16* __restrict__ xn,     // [TT*BB][CP]
        const bf16* __restrict__ WihP,   // [GG][CP]
        const bf16* __restrict__ WhhP,   // [GG][DD]
        const bf16* __restrict__ WeffP,  // [GG][DD]
        const float* __restrict__ bsum, const float* __restrict__ beff,
        bf16* __restrict__ hA, bf16* __restrict__ hB,
        bf16* __restrict__ Hdec,         // [PP][BB][DD]; Hdec[0] = enc final h
        unsigned int* __restrict__ bar) {
    // padded LDS: row pitch 520/360 shorts -> 2-way-max bank aliasing (free)
    __shared__ unsigned short Wxs[64][360];   // Wih slice   (45 KB)
    __shared__ unsigned short Whs[64][520];   // Whh -> Weff (65 KB)

    const int tid = threadIdx.x;
    const int w = tid >> 6, lane = tid & 63;
    const int quad = lane >> 4, col = lane & 15;
    const int dt = blockIdx.x & 31;          // d-tile
    const int bt = blockIdx.x >> 5;          // b-tile = barrier group
    const int d0 = dt * 16;
    const int b0 = bt * 32;
    const int arow = b0 + w * 16 + (lane & 15);   // this lane's a-row (batch)

    // ---- one-time weight staging (full rows: 44 resp. 64 uint4 per row) ----
    for (int i = tid; i < 64 * 44; i += 128) {            // Wih: 64 rows x 44 uint4
        int lr = i / 44, cu = i % 44;
        int gate = lr >> 4, rr = lr & 15;
        *((uint4*)&Wxs[lr][cu * 8]) =
            *((const uint4*)(WihP + (size_t)(gate * DD + d0 + rr) * CP) + cu);
    }
    for (int i = tid; i < 64 * 64; i += 128) {            // Whh: 64 rows x 64 uint4
        int lr = i >> 6, cu = i & 63;
        int gate = lr >> 4, rr = lr & 15;
        *((uint4*)&Whs[lr][cu * 8]) =
            *((const uint4*)(WhhP + (size_t)(gate * DD + d0 + rr) * DD) + cu);
    }
    __syncthreads();

    // per-lane persistent state
    float creg[4] = {0.f, 0.f, 0.f, 0.f};
    float bsg[4], beg[4];
#pragma unroll
    for (int gt = 0; gt < 4; ++gt) {
        bsg[gt] = bsum[gt * DD + d0 + col];
        beg[gt] = beff[gt * DD + d0 + col];
    }

    unsigned int gen = 0;

    for (int s = 0; s < NSTEPS; ++s) {
        const bool enc = (s < TT);
        const bf16* h_in;
        bf16* h_out;
        if (enc) {
            h_in  = (s & 1) ? hB : hA;
            h_out = (s == TT - 1) ? Hdec : ((s & 1) ? hA : hB);
        } else {
            int td = s - TT;                              // 0..94
            h_in  = Hdec + (size_t)td * BB * DD;
            h_out = Hdec + (size_t)(td + 1) * BB * DD;
        }

        // swap Whh -> Weff once, at the first decoder step (prev barrier's
        // trailing __syncthreads guarantees our waves are done reading Whs)
        if (s == TT) {
            for (int i = tid; i < 64 * 64; i += 128) {
                int lr = i >> 6, cu = i & 63;
                int gate = lr >> 4, rr = lr & 15;
                *((uint4*)&Whs[lr][cu * 8]) =
                    *((const uint4*)(WeffP + (size_t)(gate * DD + d0 + rr) * DD) + cu);
            }
            __syncthreads();
        }

        f32x4 acc[4] = {{0,0,0,0},{0,0,0,0},{0,0,0,0},{0,0,0,0}};

        // bulk-prefetch this lane's h a-fragments (16 x 16B, one L3 latency)
        uint4 hf[16];
        {
            const uint4* hp = (const uint4*)(h_in + (size_t)arow * DD) + quad;
#pragma unroll
            for (int ki = 0; ki < 16; ++ki) hf[ki] = hp[ki * 4];
        }

        if (enc) {
            // x-phase: K=352 from LDS-resident Wih slice
            uint4 xf[11];
            const uint4* xp = (const uint4*)(xn + (size_t)(s * BB + arow) * CP) + quad;
#pragma unroll
            for (int ki = 0; ki < 11; ++ki) xf[ki] = xp[ki * 4];
#pragma unroll
            for (int ki = 0; ki < 11; ++ki) {
                bf16x8 a = *(bf16x8*)&xf[ki];
#pragma unroll
                for (int gt = 0; gt < 4; ++gt) {
                    bf16x8 b = *(const bf16x8*)&Wxs[gt * 16 + col][ki * 32 + quad * 8];
                    acc[gt] = __builtin_amdgcn_mfma_f32_16x16x32_bf16(a, b, acc[gt], 0, 0, 0);
                }
            }
        }

        // h-phase: K=512
#pragma unroll
        for (int ki = 0; ki < 16; ++ki) {
            bf16x8 a = *(bf16x8*)&hf[ki];
#pragma unroll
            for (int gt = 0; gt < 4; ++gt) {
                bf16x8 b = *(const bf16x8*)&Whs[gt * 16 + col][ki * 32 + quad * 8];
                acc[gt] = __builtin_amdgcn_mfma_f32_16x16x32_bf16(a, b, acc[gt], 0, 0, 0);
            }
        }

        // epilogue: gates [i,f,g,o]; c stays in registers
        float bi = enc ? bsg[0] : beg[0];
        float bf_ = enc ? bsg[1] : beg[1];
        float bg = enc ? bsg[2] : beg[2];
        float bo = enc ? bsg[3] : beg[3];
#pragma unroll
        for (int r = 0; r < 4; ++r) {
            float iv = acc[0][r] + bi;
            float fv = acc[1][r] + bf_;
            float gv = acc[2][r] + bg;
            float ov = acc[3][r] + bo;
            float si = 1.f / (1.f + __expf(-iv));
            float sf = 1.f / (1.f + __expf(-fv));
            float so = 1.f / (1.f + __expf(-ov));
            float tg = tanhf(gv);
            float cc = sf * creg[r] + si * tg;
            creg[r] = cc;
            float hv = so * tanhf(cc);
            int b = b0 + w * 16 + quad * 4 + r;
            h_out[(size_t)b * DD + d0 + col] = __float2bfloat16(hv);
        }

        // inter-step barrier among the 32 blocks sharing this b-tile
        if (s < NSTEPS - 1) {
            ++gen;
            __threadfence();                 // release: drain + make agent-visible
            __syncthreads();
            if (tid == 0) {
                __hip_atomic_fetch_add(&bar[bt * 32], 1u, __ATOMIC_RELEASE,
                                       __HIP_MEMORY_SCOPE_AGENT);
                unsigned int tgt = gen * 32u;
                while (__hip_atomic_load(&bar[bt * 32], __ATOMIC_ACQUIRE,
                                         __HIP_MEMORY_SCOPE_AGENT) < tgt)
                    __builtin_amdgcn_s_sleep(2);
            }
            __syncthreads();
            __threadfence();                 // acquire: invalidate stale caches
        }
    }
}

// ---------------------------------------------------------------------------
extern "C" void kernel_launch(void* const* d_in, const int* in_sizes, int n_in,
                              void* d_out, int out_size, void* d_ws, size_t ws_size,
                              hipStream_t stream) {
    (void)in_sizes; (void)n_in; (void)out_size;
    const float* x_enc = (const float*)d_in[0];
    const float* Wih   = (const float*)d_in[1];
    const float* Whh   = (const float*)d_in[2];
    const float* bih   = (const float*)d_in[3];
    const float* bhh   = (const float*)d_in[4];
    const float* Wp    = (const float*)d_in[5];
    const float* bp    = (const float*)d_in[6];
    float* out = (float*)d_out;

    // workspace layout (all chunks 256B-aligned)
    char* ws = (char*)d_ws;
    size_t off = 0;
    float* meanp = (float*)(ws + off); off += (size_t)BB * CC * 4;
    float* stdp  = (float*)(ws + off); off += (size_t)BB * CC * 4;
    bf16* xnormP = (bf16*)(ws + off);  off += (size_t)TT * BB * CP * 2;
    bf16* WihP   = (bf16*)(ws + off);  off += (size_t)GG * CP * 2;
    bf16* WhhP   = (bf16*)(ws + off);  off += (size_t)GG * DD * 2;
    bf16* WeffP  = (bf16*)(ws + off);  off += (size_t)GG * DD * 2;
    bf16* WpTP   = (bf16*)(ws + off);  off += (size_t)DD * CP * 2;
    bf16* WpP    = (bf16*)(ws + off);  off += (size_t)384 * DD * 2;
    float* bsum  = (float*)(ws + off); off += (size_t)GG * 4;
    float* beff  = (float*)(ws + off); off += (size_t)GG * 4;
    bf16* hA     = (bf16*)(ws + off);  off += (size_t)BB * DD * 2;
    bf16* hB     = (bf16*)(ws + off);  off += (size_t)BB * DD * 2;
    bf16* Hdec   = (bf16*)(ws + off);  off += (size_t)PP * BB * DD * 2;
    unsigned int* bar = (unsigned int*)(ws + off); off += 1024;   // 8 ctrs, 128B apart
    if (ws_size < off) return;  // ~50 MB needed

    // zero-init (ws is re-poisoned before every timed call)
    hipMemsetAsync(xnormP, 0, (size_t)TT * BB * CP * 2, stream);
    hipMemsetAsync(WihP,   0, (size_t)GG * CP * 2, stream);
    hipMemsetAsync(WpTP,   0, (size_t)DD * CP * 2, stream);
    hipMemsetAsync(WpP,    0, (size_t)384 * DD * 2, stream);
    hipMemsetAsync(hA,     0, (size_t)BB * DD * 2, stream);
    hipMemsetAsync(bar,    0, 1024, stream);

    norm_kernel<<<(BB * CC + 255) / 256, 256, 0, stream>>>(x_enc, meanp, stdp, xnormP);
    cast_pad_kernel<<<(GG * CC + 255) / 256, 256, 0, stream>>>(Wih, WihP, GG, CC, CP);
    cast_pad_kernel<<<(GG * DD + 255) / 256, 256, 0, stream>>>(Whh, WhhP, GG, DD, DD);
    cast_pad_kernel<<<(CC * DD + 255) / 256, 256, 0, stream>>>(Wp, WpP, CC, DD, DD);
    transpose_wp_kernel<<<(DD * CC + 255) / 256, 256, 0, stream>>>(Wp, WpTP);
    bias_kernel<<<GG / 256, 256, 0, stream>>>(Wih, bih, bhh, bp, bsum, beff);
    weff_kernel<<<dim3(DD / 64, GG / 64), 256, 0, stream>>>(WihP, WpTP, Whh, WeffP);

    // the whole 191-step recurrence in one cooperative launch
    const bf16* xn_c = xnormP;  const bf16* wih_c = WihP;
    const bf16* whh_c = WhhP;   const bf16* weff_c = WeffP;
    const float* bs_c = bsum;   const float* be_c = beff;
    bf16* hA_c = hA; bf16* hB_c = hB; bf16* hd_c = Hdec; unsigned int* bar_c = bar;
    void* args[] = {&xn_c, &wih_c, &whh_c, &weff_c, &bs_c, &be_c,
                    &hA_c, &hB_c, &hd_c, &bar_c};
    hipLaunchCooperativeKernel((void*)lstm_persistent, dim3(256), dim3(128),
                               args, 0, stream);

    // ys = Hdec @ Wp^T + bp, denormalize, write output
    proj_kernel<<<dim3(PP * BB / 64, 384 / 64), 256, 0, stream>>>(
        Hdec, WpP, bp, stdp, meanp, out);
}

// Round 4
// 1382.895 us; speedup vs baseline: 4.3381x; 4.3381x over previous
//
#include <hip/hip_runtime.h>
#include <hip/hip_bf16.h>
#include <math.h>

#define BB 256      // batch
#define TT 96       // seq len
#define PP 96       // pred len
#define CC 321      // enc_in
#define CP 352      // padded enc_in (11*32)
#define DD 512      // d_model
#define GG 2048     // 4*DD
#define NSTEPS 191  // 96 encoder + 95 decoder (decoder step 96 output is unused)

typedef __attribute__((ext_vector_type(8))) short bf16x8;
typedef __attribute__((ext_vector_type(4))) float f32x4;
typedef __hip_bfloat16 bf16;
typedef unsigned long long u64;

// ---------------------------------------------------------------------------
// Instance norm over time: mean/stdev per (b,c); write normalized x to
// xnorm[t][b][c] (bf16, row pitch CP, pad cols pre-zeroed by memset).
__global__ void norm_kernel(const float* __restrict__ x, float* __restrict__ meanp,
                            float* __restrict__ stdp, bf16* __restrict__ xn) {
    int g = blockIdx.x * 256 + threadIdx.x;      // 0 .. BB*CC-1
    if (g >= BB * CC) return;
    int b = g / CC, c = g % CC;
    const float* xp = x + b * TT * CC + c;
    float s = 0.f;
    for (int t = 0; t < TT; ++t) s += xp[t * CC];
    float mu = s * (1.f / TT);
    float v = 0.f;
    for (int t = 0; t < TT; ++t) { float d0 = xp[t * CC] - mu; v += d0 * d0; }
    float sd = sqrtf(v * (1.f / TT) + 1e-5f);
    float rs = 1.f / sd;
    meanp[g] = mu;
    stdp[g] = sd;
    for (int t = 0; t < TT; ++t)
        xn[(t * BB + b) * CP + c] = __float2bfloat16((xp[t * CC] - mu) * rs);
}

// Cast fp32 [rows][cols] -> bf16 [rows][ldd] (pad cols pre-zeroed if ldd>cols)
__global__ void cast_pad_kernel(const float* __restrict__ src, bf16* __restrict__ dst,
                                int rows, int cols, int ldd) {
    int i = blockIdx.x * 256 + threadIdx.x;
    if (i >= rows * cols) return;
    int r = i / cols, c = i % cols;
    dst[r * ldd + c] = __float2bfloat16(src[i]);
}

// WpT[d][c] = Wp[c][d]  (bf16, row pitch CP, pad pre-zeroed)
__global__ void transpose_wp_kernel(const float* __restrict__ wp, bf16* __restrict__ wpt) {
    int i = blockIdx.x * 256 + threadIdx.x;      // over DD*CC
    if (i >= DD * CC) return;
    int d = i / CC, c = i % CC;
    wpt[d * CP + c] = __float2bfloat16(wp[c * DD + d]);
}

// bsum[j] = bih+bhh ; beff[j] = bih+bhh + dot(Wih[j,:], bp)   (fp32)
__global__ void bias_kernel(const float* __restrict__ Wih, const float* __restrict__ bih,
                            const float* __restrict__ bhh, const float* __restrict__ bp,
                            float* __restrict__ bsum, float* __restrict__ beff) {
    int j = blockIdx.x * 256 + threadIdx.x;      // 2048
    if (j >= GG) return;
    float s = bih[j] + bhh[j];
    float acc = 0.f;
    const float* w = Wih + j * CC;
    for (int c = 0; c < CC; ++c) acc += w[c] * bp[c];
    bsum[j] = s;
    beff[j] = s + acc;
}

// ---------------------------------------------------------------------------
// Generic 64x64 block MFMA core: C[m][n] = sum_k A[m][k] * Bt[n][k]
__device__ __forceinline__ void gemm_core_64x64(const bf16* A, int lda, const bf16* Bt,
                                                int ldb, int K, int m0, int n0,
                                                f32x4 acc[4]) {
    __shared__ unsigned short As[64][40];
    __shared__ unsigned short Bs[64][40];
    int tid = threadIdx.x;
    int w = tid >> 6, lane = tid & 63;
    int quad = lane >> 4, col = lane & 15;
    int lr = tid >> 2, lc = (tid & 3) * 8;
    for (int k0 = 0; k0 < K; k0 += 32) {
        __syncthreads();
        *(uint4*)&As[lr][lc] = *(const uint4*)&A[(size_t)(m0 + lr) * lda + k0 + lc];
        *(uint4*)&Bs[lr][lc] = *(const uint4*)&Bt[(size_t)(n0 + lr) * ldb + k0 + lc];
        __syncthreads();
        bf16x8 a = *(const bf16x8*)&As[w * 16 + col][quad * 8];
#pragma unroll
        for (int nt = 0; nt < 4; ++nt) {
            bf16x8 bfr = *(const bf16x8*)&Bs[nt * 16 + col][quad * 8];
            acc[nt] = __builtin_amdgcn_mfma_f32_16x16x32_bf16(a, bfr, acc[nt], 0, 0, 0);
        }
    }
}

// Weff[j][d] = Whh[j][d] + sum_c Wih[j][c]*Wp[c][d]   (bf16 out)
__global__ void weff_kernel(const bf16* __restrict__ WihP, const bf16* __restrict__ WpTP,
                            const float* __restrict__ Whh, bf16* __restrict__ WeffP) {
    f32x4 acc[4] = {{0,0,0,0},{0,0,0,0},{0,0,0,0},{0,0,0,0}};
    int m0 = blockIdx.y * 64, n0 = blockIdx.x * 64;
    gemm_core_64x64(WihP, CP, WpTP, CP, CP, m0, n0, acc);
    int tid = threadIdx.x, w = tid >> 6, lane = tid & 63;
    int quad = lane >> 4, col = lane & 15;
#pragma unroll
    for (int nt = 0; nt < 4; ++nt)
#pragma unroll
        for (int r = 0; r < 4; ++r) {
            int j = m0 + w * 16 + quad * 4 + r;
            int d = n0 + nt * 16 + col;
            WeffP[j * DD + d] = __float2bfloat16(acc[nt][r] + Whh[j * DD + d]);
        }
}

// Final projection + denorm: out[b][t][c] = (Hdec[t*BB+b,:]@Wp[c,:] + bp[c])*std + mean
__global__ void proj_kernel(const bf16* __restrict__ Hdec, const bf16* __restrict__ WpP,
                            const float* __restrict__ bp, const float* __restrict__ stdp,
                            const float* __restrict__ meanp, float* __restrict__ out) {
    f32x4 acc[4] = {{0,0,0,0},{0,0,0,0},{0,0,0,0},{0,0,0,0}};
    int m0 = blockIdx.x * 64, n0 = blockIdx.y * 64;
    gemm_core_64x64(Hdec, DD, WpP, DD, DD, m0, n0, acc);
    int tid = threadIdx.x, w = tid >> 6, lane = tid & 63;
    int quad = lane >> 4, col = lane & 15;
#pragma unroll
    for (int nt = 0; nt < 4; ++nt) {
        int c = n0 + nt * 16 + col;
        if (c >= CC) continue;
        float bpc = bp[c];
#pragma unroll
        for (int r = 0; r < 4; ++r) {
            int row = m0 + w * 16 + quad * 4 + r;   // = t*BB + b
            int t = row >> 8, b = row & 255;
            float y = acc[nt][r] + bpc;
            int sc = b * CC + c;
            out[(b * PP + t) * CC + c] = y * stdp[sc] + meanp[sc];
        }
    }
}

// ---------------------------------------------------------------------------
// Persistent recurrence kernel, fence-free edition.
// 256 blocks x 128 threads, 1 block/CU (108 KB LDS), cooperative launch.
// Block (bt,dt): batches bt*32..+31, gate rows j = gate*512 + dt*16..+15.
// Operand-swapped MFMA: A=W (m=j), B=h (n=batch) -> lane's 4 acc values per
// gate are 4 consecutive d for ONE batch -> single 8B packed h store.
// h crosses blocks via relaxed AGENT-scope atomics (sc1: bypass non-coherent
// per-XCD L2, hit MALL coherent point) -> NO buffer_inv/wbl2 in the loop
// (R3's 30us/step was the per-poll ACQUIRE buffer_inv).
// LDS weights in fragment-linear order -> conflict-free ds_read_b128.
__global__ __launch_bounds__(128, 1) void lstm_persistent(
        const bf16* __restrict__ xn,     // [TT*BB][CP]
        const bf16* __restrict__ WihP,   // [GG][CP]
        const bf16* __restrict__ WhhP,   // [GG][DD]
        const bf16* __restrict__ WeffP,  // [GG][DD]
        const float* __restrict__ bsum, const float* __restrict__ beff,
        bf16* __restrict__ hA, bf16* __restrict__ hB,
        bf16* __restrict__ Hdec,         // [PP][BB][DD]; Hdec[0] = enc final h
        unsigned int* __restrict__ bar) {
    // fragment-linear LDS: Whs[gt][ki][col][32], Wxs[gt][ki][col][32]
    __shared__ unsigned short Whs[4 * 16 * 16 * 32];   // 64 KB
    __shared__ unsigned short Wxs[4 * 11 * 16 * 32];   // 44 KB

    const int tid = threadIdx.x;
    const int w = tid >> 6, lane = tid & 63;
    const int quad = lane >> 4, col = lane & 15;
    const int dt = blockIdx.x & 31;          // d-tile
    const int bt = blockIdx.x >> 5;          // b-tile = barrier group
    const int d0 = dt * 16;
    const int b0 = bt * 32;
    const int batch = b0 + w * 16 + col;     // this lane's batch (B-frag n)

    // ---- one-time weight staging into fragment-linear LDS ----
    for (int i = tid; i < 64 * 44; i += 128) {           // Wih: 64 rows x 44 chunks
        int row = i / 44, c8 = i % 44;
        int gt = row >> 4, cl = row & 15;
        int ki = c8 >> 2, q = c8 & 3;
        *(uint4*)&Wxs[((gt * 11 + ki) * 16 + cl) * 32 + q * 8] =
            *((const uint4*)(WihP + (size_t)(gt * DD + d0 + cl) * CP) + c8);
    }
    for (int i = tid; i < 64 * 64; i += 128) {           // Whh: 64 rows x 64 chunks
        int row = i >> 6, c8 = i & 63;
        int gt = row >> 4, cl = row & 15;
        int ki = c8 >> 2, q = c8 & 3;
        *(uint4*)&Whs[((gt * 16 + ki) * 16 + cl) * 32 + q * 8] =
            *((const uint4*)(WhhP + (size_t)(gt * DD + d0 + cl) * DD) + c8);
    }
    __syncthreads();

    // per-lane persistent state: c for (batch, d0+quad*4+r)
    float creg[4] = {0.f, 0.f, 0.f, 0.f};
    float bs_[16], be_[16];                  // [gate*4 + r], d = d0+quad*4+r
#pragma unroll
    for (int g4 = 0; g4 < 16; ++g4) {
        int gt = g4 >> 2, r = g4 & 3;
        bs_[g4] = bsum[gt * DD + d0 + quad * 4 + r];
        be_[g4] = beff[gt * DD + d0 + quad * 4 + r];
    }

    unsigned int gen = 0;

    for (int s = 0; s < NSTEPS; ++s) {
        const bool enc = (s < TT);
        const bf16* h_in;
        bf16* h_out;
        if (enc) {
            h_in  = (s & 1) ? hB : hA;
            h_out = (s == TT - 1) ? Hdec : ((s & 1) ? hA : hB);
        } else {
            int td = s - TT;                              // 0..94
            h_in  = Hdec + (size_t)td * BB * DD;
            h_out = Hdec + (size_t)(td + 1) * BB * DD;
        }

        // swap Whh -> Weff once at first decoder step (prev barrier's trailing
        // __syncthreads guarantees all waves are done reading Whs)
        if (s == TT) {
            for (int i = tid; i < 64 * 64; i += 128) {
                int row = i >> 6, c8 = i & 63;
                int gt = row >> 4, cl = row & 15;
                int ki = c8 >> 2, q = c8 & 3;
                *(uint4*)&Whs[((gt * 16 + ki) * 16 + cl) * 32 + q * 8] =
                    *((const uint4*)(WeffP + (size_t)(gt * DD + d0 + cl) * DD) + c8);
            }
            __syncthreads();
        }

        f32x4 acc[4] = {{0,0,0,0},{0,0,0,0},{0,0,0,0},{0,0,0,0}};

        // bulk-prefetch h B-fragments: 32 x 8B relaxed agent atomics (sc1 ->
        // MALL coherent point; always fresh, no acquire fence needed)
        u64 hf[32];
        {
            u64* hp = (u64*)(h_in + (size_t)batch * DD);
#pragma unroll
            for (int ki = 0; ki < 16; ++ki) {
                hf[2 * ki] = __hip_atomic_load(&hp[ki * 8 + quad * 2],
                                               __ATOMIC_RELAXED, __HIP_MEMORY_SCOPE_AGENT);
                hf[2 * ki + 1] = __hip_atomic_load(&hp[ki * 8 + quad * 2 + 1],
                                                   __ATOMIC_RELAXED, __HIP_MEMORY_SCOPE_AGENT);
            }
        }

        if (enc) {
            // x-phase: K=352; xn is static (plain cached loads fine)
            uint4 xf[11];
            const uint4* xp = (const uint4*)(xn + (size_t)(s * BB + batch) * CP) + quad;
#pragma unroll
            for (int ki = 0; ki < 11; ++ki) xf[ki] = xp[ki * 4];
#pragma unroll
            for (int ki = 0; ki < 11; ++ki) {
                bf16x8 xv = *(bf16x8*)&xf[ki];
#pragma unroll
                for (int gt = 0; gt < 4; ++gt) {
                    bf16x8 wf = *(const bf16x8*)&Wxs[((gt * 11 + ki) * 16 + col) * 32 + quad * 8];
                    acc[gt] = __builtin_amdgcn_mfma_f32_16x16x32_bf16(wf, xv, acc[gt], 0, 0, 0);
                }
            }
        }

        // h-phase: K=512
#pragma unroll
        for (int ki = 0; ki < 16; ++ki) {
            union { u64 q[2]; bf16x8 v; } hu;
            hu.q[0] = hf[2 * ki];
            hu.q[1] = hf[2 * ki + 1];
#pragma unroll
            for (int gt = 0; gt < 4; ++gt) {
                bf16x8 wf = *(const bf16x8*)&Whs[((gt * 16 + ki) * 16 + col) * 32 + quad * 8];
                acc[gt] = __builtin_amdgcn_mfma_f32_16x16x32_bf16(wf, hu.v, acc[gt], 0, 0, 0);
            }
        }

        // epilogue: gates [i,f,g,o]; lane owns d = d0+quad*4+(0..3) for `batch`
        u64 pack = 0;
#pragma unroll
        for (int r = 0; r < 4; ++r) {
            float iv = acc[0][r] + (enc ? bs_[0 + r] : be_[0 + r]);
            float fv = acc[1][r] + (enc ? bs_[4 + r] : be_[4 + r]);
            float gv = acc[2][r] + (enc ? bs_[8 + r] : be_[8 + r]);
            float ov = acc[3][r] + (enc ? bs_[12 + r] : be_[12 + r]);
            float si = 1.f / (1.f + __expf(-iv));
            float sf = 1.f / (1.f + __expf(-fv));
            float so = 1.f / (1.f + __expf(-ov));
            float tg = tanhf(gv);
            float cc = sf * creg[r] + si * tg;
            creg[r] = cc;
            float hv = so * tanhf(cc);
            union { bf16 h; unsigned short u; } cv;
            cv.h = __float2bfloat16(hv);
            pack |= (u64)cv.u << (16 * r);
        }
        __hip_atomic_store((u64*)&h_out[(size_t)batch * DD + d0 + quad * 4], pack,
                           __ATOMIC_RELAXED, __HIP_MEMORY_SCOPE_AGENT);

        // inter-step barrier among the 32 blocks sharing this b-tile.
        // Monotone counter; RELAXED everywhere -> no cache maintenance.
        // __syncthreads drains each wave's vmcnt (sc1 stores at MALL) first.
        if (s < NSTEPS - 1) {
            ++gen;
            __builtin_amdgcn_s_waitcnt(0);   // belt-and-braces store drain
            __syncthreads();
            if (tid == 0) {
                __hip_atomic_fetch_add(&bar[bt * 32], 1u, __ATOMIC_RELAXED,
                                       __HIP_MEMORY_SCOPE_AGENT);
                unsigned int tgt = gen * 32u;
                while (__hip_atomic_load(&bar[bt * 32], __ATOMIC_RELAXED,
                                         __HIP_MEMORY_SCOPE_AGENT) < tgt)
                    __builtin_amdgcn_s_sleep(1);
            }
            __syncthreads();
        }
    }
}

// ---------------------------------------------------------------------------
extern "C" void kernel_launch(void* const* d_in, const int* in_sizes, int n_in,
                              void* d_out, int out_size, void* d_ws, size_t ws_size,
                              hipStream_t stream) {
    (void)in_sizes; (void)n_in; (void)out_size;
    const float* x_enc = (const float*)d_in[0];
    const float* Wih   = (const float*)d_in[1];
    const float* Whh   = (const float*)d_in[2];
    const float* bih   = (const float*)d_in[3];
    const float* bhh   = (const float*)d_in[4];
    const float* Wp    = (const float*)d_in[5];
    const float* bp    = (const float*)d_in[6];
    float* out = (float*)d_out;

    // workspace layout (all chunks 256B-aligned)
    char* ws = (char*)d_ws;
    size_t off = 0;
    float* meanp = (float*)(ws + off); off += (size_t)BB * CC * 4;
    float* stdp  = (float*)(ws + off); off += (size_t)BB * CC * 4;
    bf16* xnormP = (bf16*)(ws + off);  off += (size_t)TT * BB * CP * 2;
    bf16* WihP   = (bf16*)(ws + off);  off += (size_t)GG * CP * 2;
    bf16* WhhP   = (bf16*)(ws + off);  off += (size_t)GG * DD * 2;
    bf16* WeffP  = (bf16*)(ws + off);  off += (size_t)GG * DD * 2;
    bf16* WpTP   = (bf16*)(ws + off);  off += (size_t)DD * CP * 2;
    bf16* WpP    = (bf16*)(ws + off);  off += (size_t)384 * DD * 2;
    float* bsum  = (float*)(ws + off); off += (size_t)GG * 4;
    float* beff  = (float*)(ws + off); off += (size_t)GG * 4;
    bf16* hA     = (bf16*)(ws + off);  off += (size_t)BB * DD * 2;
    bf16* hB     = (bf16*)(ws + off);  off += (size_t)BB * DD * 2;
    bf16* Hdec   = (bf16*)(ws + off);  off += (size_t)PP * BB * DD * 2;
    unsigned int* bar = (unsigned int*)(ws + off); off += 1024;   // 8 ctrs, 128B apart
    if (ws_size < off) return;  // ~50 MB needed

    // zero-init (ws is re-poisoned before every timed call)
    hipMemsetAsync(xnormP, 0, (size_t)TT * BB * CP * 2, stream);
    hipMemsetAsync(WihP,   0, (size_t)GG * CP * 2, stream);
    hipMemsetAsync(WpTP,   0, (size_t)DD * CP * 2, stream);
    hipMemsetAsync(WpP,    0, (size_t)384 * DD * 2, stream);
    hipMemsetAsync(hA,     0, (size_t)BB * DD * 2, stream);
    hipMemsetAsync(bar,    0, 1024, stream);

    norm_kernel<<<(BB * CC + 255) / 256, 256, 0, stream>>>(x_enc, meanp, stdp, xnormP);
    cast_pad_kernel<<<(GG * CC + 255) / 256, 256, 0, stream>>>(Wih, WihP, GG, CC, CP);
    cast_pad_kernel<<<(GG * DD + 255) / 256, 256, 0, stream>>>(Whh, WhhP, GG, DD, DD);
    cast_pad_kernel<<<(CC * DD + 255) / 256, 256, 0, stream>>>(Wp, WpP, CC, DD, DD);
    transpose_wp_kernel<<<(DD * CC + 255) / 256, 256, 0, stream>>>(Wp, WpTP);
    bias_kernel<<<GG / 256, 256, 0, stream>>>(Wih, bih, bhh, bp, bsum, beff);
    weff_kernel<<<dim3(DD / 64, GG / 64), 256, 0, stream>>>(WihP, WpTP, Whh, WeffP);

    // the whole 191-step recurrence in one cooperative launch
    const bf16* xn_c = xnormP;  const bf16* wih_c = WihP;
    const bf16* whh_c = WhhP;   const bf16* weff_c = WeffP;
    const float* bs_c = bsum;   const float* be_c = beff;
    bf16* hA_c = hA; bf16* hB_c = hB; bf16* hd_c = Hdec; unsigned int* bar_c = bar;
    void* args[] = {&xn_c, &wih_c, &whh_c, &weff_c, &bs_c, &be_c,
                    &hA_c, &hB_c, &hd_c, &bar_c};
    hipLaunchCooperativeKernel((void*)lstm_persistent, dim3(256), dim3(128),
                               args, 0, stream);

    // ys = Hdec @ Wp^T + bp, denormalize, write output
    proj_kernel<<<dim3(PP * BB / 64, 384 / 64), 256, 0, stream>>>(
        Hdec, WpP, bp, stdp, meanp, out);
}